// Round 5
// baseline (125.837 us; speedup 1.0000x reference)
//
#include <hip/hip_runtime.h>
#include <hip/hip_fp16.h>

#define PP 9216   // 96*96 pixels per batch

typedef _Float16 f16x8 __attribute__((ext_vector_type(8)));
typedef _Float16 f16x4 __attribute__((ext_vector_type(4)));
typedef _Float16 h2    __attribute__((ext_vector_type(2)));
typedef float    f32x4 __attribute__((ext_vector_type(4)));

// LDS: two 16KB regions, 32768 total -> exactly 5 blocks/CU.
//  Region A (0..16384):    sX[64][128] swz   -> after B2: sP (4x2304B) + sQ/sAo (4096B at 9216)
//  Region B (16384..32768): sK[64][128] swz  -> after B3: sVT 4 wave-slabs [32][64] swz
#define LDS_BYTES 32768

// swizzled half-index within a 128-half (256B, 16x16B-chunk) row
__device__ __forceinline__ int swz128(int row, int hc) {
    return row * 128 + (((hc >> 3) ^ (row & 15)) << 3) + (hc & 7);
}
// swizzled half-index within a 64-half (128B, 8x16B-chunk) row
__device__ __forceinline__ int swz64(int row, int hc) {
    return row * 64 + (((hc >> 3) ^ (row & 7)) << 3) + (hc & 7);
}

// ---------------------------------------------------------------------------
// prep_w: one-time f32 -> f16 weight conversion.
// wqkv16[o][c], o in [0,384): 0-127 wq, 128-255 wk, 256-383 wv. wp16[c][o].
// ---------------------------------------------------------------------------
__global__ __launch_bounds__(256) void prep_w(
    const float* __restrict__ wq, const float* __restrict__ wk,
    const float* __restrict__ wv, const float* __restrict__ wp,
    _Float16* __restrict__ wqkv16, _Float16* __restrict__ wp16)
{
    int e = (blockIdx.x * 256 + threadIdx.x) * 4;   // 4 elems/thread, 65536 total
    const float* src;
    _Float16* dst;
    if (e < 49152) {
        int o = e >> 7;
        src = (o < 128) ? (wq + (size_t)o * 128)
            : (o < 256) ? (wk + (size_t)(o - 128) * 128)
                        : (wv + (size_t)(o - 256) * 128);
        src += (e & 127);
        dst = wqkv16 + e;
    } else {
        int j = e - 49152;
        src = wp + j;
        dst = wp16 + j;
    }
    float4 v = *(const float4*)src;
    f16x4 h;
    h[0] = (_Float16)v.x; h[1] = (_Float16)v.y;
    h[2] = (_Float16)v.z; h[3] = (_Float16)v.w;
    *(f16x4*)dst = h;
}

// ---------------------------------------------------------------------------
// Fully fused window self-attention, 4x4 px tile (8x8 halo), 4 waves,
// wave w owns head w. 4 barriers. 32KB LDS -> 5 blocks/CU -> whole grid
// (1152 blocks) resident in one round. Softmax in MFMA-fragment registers.
// ---------------------------------------------------------------------------
__global__ __launch_bounds__(256, 5) void fused_attn(
    const float* __restrict__ x, const _Float16* __restrict__ wqkv,
    const _Float16* __restrict__ wp16, float* __restrict__ out)
{
    __shared__ __align__(16) char smem[LDS_BYTES];
    _Float16* sA = (_Float16*)smem;             // sX -> sP/sQ/sAo
    _Float16* sB = (_Float16*)(smem + 16384);   // sK -> sVT

    const int t = threadIdx.x;
    const int w = t >> 6, lane = t & 63, lm = lane & 15, quad = lane >> 4;

    // XCD-bijective swizzle: 1152 = 8 XCDs x 144 contiguous blocks
    const int wgid = (blockIdx.x & 7) * 144 + (blockIdx.x >> 3);
    const int b = wgid / 576;
    const int rem = wgid - b * 576;
    const int x0 = (rem % 24) * 4, y0 = (rem / 24) * 4;

    const float* xb = x + (size_t)b * 128 * PP;
    float* ob = out + (size_t)b * 128 * PP;

    // ---- P1: stage 8x8 halo x 128ch, f32 -> f16 transposed into sX[pos][c]
    {
        const int pos = (t & 31) * 2;
        const int gy = y0 - 2 + (pos >> 3);
        const int gx = x0 - 2 + (pos & 7);         // even; float2 never straddles
        const bool inb = ((unsigned)gy < 96u) && ((unsigned)gx < 96u);
        const float* src = xb + (size_t)(t >> 5) * PP + gy * 96 + gx;
        float2 vv[16];
        #pragma unroll
        for (int i = 0; i < 16; i++)
            vv[i] = inb ? *(const float2*)(src + (size_t)(i * 8) * PP)
                        : make_float2(0.f, 0.f);
        #pragma unroll
        for (int i = 0; i < 16; i++) {
            int c = i * 8 + (t >> 5);
            sA[swz128(pos,     c)] = (_Float16)vv[i].x;
            sA[swz128(pos + 1, c)] = (_Float16)vv[i].y;
        }
    }
    __syncthreads();                      // B1: sX ready

    // ---- P2: K,V GEMM over 64 halo positions (m-outer; weight frags re-read,
    // L1-hot). K N-tiles {w,w+4} -> sK; V tiles {2w,2w+1} (head w) -> registers.
    h2 vpk[2][4][2];
    #pragma unroll
    for (int m = 0; m < 4; m++) {
        f16x8 A[4];
        #pragma unroll
        for (int kc = 0; kc < 4; kc++)
            A[kc] = *(const f16x8*)(sA + swz128(m * 16 + lm, kc * 32 + quad * 8));
        #pragma unroll
        for (int ni = 0; ni < 4; ni++) {
            const int wrow = (ni < 2) ? (128 + (w + 4 * ni) * 16 + lm)
                                      : (256 + (2 * w + (ni - 2)) * 16 + lm);
            const _Float16* wr = wqkv + (size_t)wrow * 128;
            f32x4 acc = {0.f, 0.f, 0.f, 0.f};
            #pragma unroll
            for (int kc = 0; kc < 4; kc++)
                acc = __builtin_amdgcn_mfma_f32_16x16x32_f16(
                    A[kc], *(const f16x8*)(wr + kc * 32 + quad * 8), acc, 0, 0, 0);
            if (ni < 2) {
                int n = w + 4 * ni;
                #pragma unroll
                for (int r = 0; r < 4; r++)
                    sB[swz128(m * 16 + quad * 4 + r, n * 16 + lm)] = (_Float16)acc[r];
            } else {
                h2 p0, p1;
                p0[0] = (_Float16)acc[0]; p0[1] = (_Float16)acc[1];
                p1[0] = (_Float16)acc[2]; p1[1] = (_Float16)acc[3];
                vpk[ni - 2][m][0] = p0;
                vpk[ni - 2][m][1] = p1;
            }
        }
    }

    // ---- P3a: A-frags for Q (interior halo rows) into regs before sX dies
    f16x8 A3[4];
    {
        int hrow = ((lm >> 2) + 2) * 8 + (lm & 3) + 2;
        #pragma unroll
        for (int kc = 0; kc < 4; kc++)
            A3[kc] = *(const f16x8*)(sA + swz128(hrow, kc * 32 + quad * 8));
    }
    __syncthreads();                      // B2: all sX reads done; sK complete

    // ---- P3b: Q GEMM; wave w computes head w's own Q channels {2w,2w+1}
    _Float16* sQ = sA + 4608;             // bytes 9216..13312 (old sX rows 36+)
    #pragma unroll
    for (int nn = 0; nn < 2; nn++) {
        const _Float16* wr = wqkv + (size_t)((2 * w + nn) * 16 + lm) * 128;
        f32x4 acc = {0.f, 0.f, 0.f, 0.f};
        #pragma unroll
        for (int kc = 0; kc < 4; kc++)
            acc = __builtin_amdgcn_mfma_f32_16x16x32_f16(
                A3[kc], *(const f16x8*)(wr + kc * 32 + quad * 8), acc, 0, 0, 0);
        #pragma unroll
        for (int r = 0; r < 4; r++)
            sQ[swz128(quad * 4 + r, (2 * w + nn) * 16 + lm)] = (_Float16)acc[r];
    }

    // ---- QK^T: S[px=quad*4+r][pos=n*16+lm] fragments (same-wave sQ dep only)
    f32x4 S[4];
    {
        f16x8 Aq = *(const f16x8*)(sQ + swz128(lm, w * 32 + quad * 8));
        #pragma unroll
        for (int n = 0; n < 4; n++) {
            f16x8 Bk = *(const f16x8*)(sB + swz128(n * 16 + lm, w * 32 + quad * 8));
            f32x4 z = {0.f, 0.f, 0.f, 0.f};
            S[n] = __builtin_amdgcn_mfma_f32_16x16x32_f16(Aq, Bk, z, 0, 0, 0);
        }
    }

    // ---- softmax on fragments. px=(quad,r): window = hy in [quad,quad+5),
    // hx in [r,r+5). Reduce over n in-lane + shfl_xor over the 16-lane group.
    _Float16* sPh = sA + w * 1152;        // head slab: 16 rows x 72 halfs
    float inv4[4];
    {
        const float scale = 0.17677669529663689f;
        #pragma unroll
        for (int r = 0; r < 4; r++) {
            float e[4];
            float mx = -1e30f;
            #pragma unroll
            for (int n = 0; n < 4; n++) {
                int hy = n * 2 + (lm >> 3), hx = lm & 7;
                bool memb = (hy >= quad) && (hy < quad + 5) && (hx >= r) && (hx < r + 5);
                e[n] = memb ? S[n][r] * scale : -1e30f;
                mx = fmaxf(mx, e[n]);
            }
            mx = fmaxf(mx, __shfl_xor(mx, 1));
            mx = fmaxf(mx, __shfl_xor(mx, 2));
            mx = fmaxf(mx, __shfl_xor(mx, 4));
            mx = fmaxf(mx, __shfl_xor(mx, 8));
            float sum = 0.f;
            #pragma unroll
            for (int n = 0; n < 4; n++) {
                float ev = __expf(e[n] - mx);   // masked -> exp(-huge) == 0
                e[n] = ev;
                sum += ev;
            }
            sum += __shfl_xor(sum, 1);
            sum += __shfl_xor(sum, 2);
            sum += __shfl_xor(sum, 4);
            sum += __shfl_xor(sum, 8);
            inv4[r] = 1.f / sum;
            #pragma unroll
            for (int n = 0; n < 4; n++)
                sPh[(quad * 4 + r) * 72 + n * 16 + lm] = (_Float16)e[n];
        }
    }
    __syncthreads();                      // B3: sK reads done; sQ dead

    // ---- stage held V registers into per-wave slab (overlays sK)
    _Float16* sVh = sB + w * 2048;        // V^T[32 d][64 pos] swz
    #pragma unroll
    for (int nn = 0; nn < 2; nn++)
        #pragma unroll
        for (int m = 0; m < 4; m++)
            #pragma unroll
            for (int rp = 0; rp < 2; rp++)
                *(h2*)(sVh + swz64(nn * 16 + lm, m * 16 + quad * 4 + rp * 2))
                    = vpk[nn][m][rp];

    // ---- PV: out[px][d] = (sum_pos P*V) * inv  (all same-wave LDS deps)
    _Float16* sAo = sQ;                   // overlays dead sQ
    {
        f16x8 Ap[2];
        #pragma unroll
        for (int kc = 0; kc < 2; kc++)
            Ap[kc] = *(const f16x8*)(sPh + lm * 72 + kc * 32 + quad * 8);
        #pragma unroll
        for (int nd = 0; nd < 2; nd++) {
            f32x4 acc = {0.f, 0.f, 0.f, 0.f};
            #pragma unroll
            for (int kc = 0; kc < 2; kc++) {
                f16x8 Bv = *(const f16x8*)(sVh + swz64(nd * 16 + lm, kc * 32 + quad * 8));
                acc = __builtin_amdgcn_mfma_f32_16x16x32_f16(Ap[kc], Bv, acc, 0, 0, 0);
            }
            #pragma unroll
            for (int r = 0; r < 4; r++)
                sAo[swz128(quad * 4 + r, w * 32 + nd * 16 + lm)] =
                    (_Float16)(acc[r] * inv4[r]);
        }
    }
    __syncthreads();                      // B4: sAo complete (all heads)

    // ---- proj: out[c][px] = sum_o wp[c][o] * ao[px][o]
    {
        f16x8 Bf[4];
        #pragma unroll
        for (int kc = 0; kc < 4; kc++)
            Bf[kc] = *(const f16x8*)(sAo + swz128(lm, kc * 32 + quad * 8));
        int gp = (y0 + (lm >> 2)) * 96 + x0 + (lm & 3);
        #pragma unroll
        for (int mi = 0; mi < 2; mi++) {
            const _Float16* wr = wp16 + (size_t)((w * 2 + mi) * 16 + lm) * 128;
            f32x4 acc = {0.f, 0.f, 0.f, 0.f};
            #pragma unroll
            for (int kc = 0; kc < 4; kc++)
                acc = __builtin_amdgcn_mfma_f32_16x16x32_f16(
                    *(const f16x8*)(wr + kc * 32 + quad * 8), Bf[kc], acc, 0, 0, 0);
            int c0 = (w * 2 + mi) * 16 + quad * 4;
            #pragma unroll
            for (int r = 0; r < 4; r++)
                ob[(size_t)(c0 + r) * PP + gp] = acc[r];
        }
    }
}

extern "C" void kernel_launch(void* const* d_in, const int* in_sizes, int n_in,
                              void* d_out, int out_size, void* d_ws, size_t ws_size,
                              hipStream_t stream)
{
    const float* x  = (const float*)d_in[0];
    const float* wq = (const float*)d_in[1];
    const float* wk = (const float*)d_in[2];
    const float* wv = (const float*)d_in[3];
    const float* wp = (const float*)d_in[4];
    float* out = (float*)d_out;

    _Float16* wqkv16 = (_Float16*)d_ws;          // 384*128
    _Float16* wp16   = wqkv16 + 49152;           // 128*128

    prep_w<<<dim3(64), 256, 0, stream>>>(wq, wk, wv, wp, wqkv16, wp16);
    fused_attn<<<dim3(1152), 256, 0, stream>>>(x, wqkv16, wp16, out);
}

// Round 6
// 106.714 us; speedup vs baseline: 1.1792x; 1.1792x over previous
//
#include <hip/hip_runtime.h>
#include <hip/hip_fp16.h>

#define PP 9216   // 96*96 pixels per batch

typedef _Float16 f16x8 __attribute__((ext_vector_type(8)));
typedef _Float16 f16x4 __attribute__((ext_vector_type(4)));
typedef _Float16 h2    __attribute__((ext_vector_type(2)));
typedef float    f32x4 __attribute__((ext_vector_type(4)));

// LDS: two 16KB regions, 32768 total.
//  Region A (0..16384):    sX[64][128] swz   -> after B2: sP (4x2304B) + sQ/sAo (4096B at 9216)
//  Region B (16384..32768): sK[64][128] swz  -> after B3: sVT 4 wave-slabs [32][64] swz
#define LDS_BYTES 32768

// swizzled half-index within a 128-half (256B, 16x16B-chunk) row
__device__ __forceinline__ int swz128(int row, int hc) {
    return row * 128 + (((hc >> 3) ^ (row & 15)) << 3) + (hc & 7);
}
// swizzled half-index within a 64-half (128B, 8x16B-chunk) row
__device__ __forceinline__ int swz64(int row, int hc) {
    return row * 64 + (((hc >> 3) ^ (row & 7)) << 3) + (hc & 7);
}

// ---------------------------------------------------------------------------
// prep_w: one-time f32 -> f16 weight conversion.
// wqkv16[o][c], o in [0,384): 0-127 wq, 128-255 wk, 256-383 wv. wp16[c][o].
// ---------------------------------------------------------------------------
__global__ __launch_bounds__(256) void prep_w(
    const float* __restrict__ wq, const float* __restrict__ wk,
    const float* __restrict__ wv, const float* __restrict__ wp,
    _Float16* __restrict__ wqkv16, _Float16* __restrict__ wp16)
{
    int e = (blockIdx.x * 256 + threadIdx.x) * 4;   // 4 elems/thread, 65536 total
    const float* src;
    _Float16* dst;
    if (e < 49152) {
        int o = e >> 7;
        src = (o < 128) ? (wq + (size_t)o * 128)
            : (o < 256) ? (wk + (size_t)(o - 128) * 128)
                        : (wv + (size_t)(o - 256) * 128);
        src += (e & 127);
        dst = wqkv16 + e;
    } else {
        int j = e - 49152;
        src = wp + j;
        dst = wp16 + j;
    }
    float4 v = *(const float4*)src;
    f16x4 h;
    h[0] = (_Float16)v.x; h[1] = (_Float16)v.y;
    h[2] = (_Float16)v.z; h[3] = (_Float16)v.w;
    *(f16x4*)dst = h;
}

// ---------------------------------------------------------------------------
// Fully fused window self-attention, 4x4 px tile (8x8 halo), 4 waves,
// wave w owns head w. 4 barriers. 32KB LDS; launch_bounds(256,4) -> 128 VGPR,
// 4 blocks/CU. K/V weight fragments held in registers across B1 (latency
// hidden under P1); Q-weights pre-issued before B2; proj-weights before B3.
// ---------------------------------------------------------------------------
__global__ __launch_bounds__(256, 4) void fused_attn(
    const float* __restrict__ x, const _Float16* __restrict__ wqkv,
    const _Float16* __restrict__ wp16, float* __restrict__ out)
{
    __shared__ __align__(16) char smem[LDS_BYTES];
    _Float16* sA = (_Float16*)smem;             // sX -> sP/sQ/sAo
    _Float16* sB = (_Float16*)(smem + 16384);   // sK -> sVT

    const int t = threadIdx.x;
    const int w = t >> 6, lane = t & 63, lm = lane & 15, quad = lane >> 4;

    // XCD-bijective swizzle: 1152 = 8 XCDs x 144 contiguous blocks
    const int wgid = (blockIdx.x & 7) * 144 + (blockIdx.x >> 3);
    const int b = wgid / 576;
    const int rem = wgid - b * 576;
    const int x0 = (rem % 24) * 4, y0 = (rem / 24) * 4;

    const float* xb = x + (size_t)b * 128 * PP;
    float* ob = out + (size_t)b * 128 * PP;

    // ---- hold K/V weight fragments in registers (issued first; latency
    // overlaps the P1 halo staging). ni 0,1 -> K N-tiles {w,w+4};
    // ni 2,3 -> V tiles {2w,2w+1} (head w's V channels).
    f16x8 BKV[4][4];
    #pragma unroll
    for (int ni = 0; ni < 4; ni++) {
        const int wrow = (ni < 2) ? (128 + (w + 4 * ni) * 16 + lm)
                                  : (256 + (2 * w + (ni - 2)) * 16 + lm);
        const _Float16* wr = wqkv + (size_t)wrow * 128;
        #pragma unroll
        for (int kc = 0; kc < 4; kc++)
            BKV[ni][kc] = *(const f16x8*)(wr + kc * 32 + quad * 8);
    }

    // ---- P1: stage 8x8 halo x 128ch, f32 -> f16 transposed into sX[pos][c]
    {
        const int pos = (t & 31) * 2;
        const int gy = y0 - 2 + (pos >> 3);
        const int gx = x0 - 2 + (pos & 7);         // even; float2 never straddles
        const bool inb = ((unsigned)gy < 96u) && ((unsigned)gx < 96u);
        const float* src = xb + (size_t)(t >> 5) * PP + gy * 96 + gx;
        float2 vv[16];
        #pragma unroll
        for (int i = 0; i < 16; i++)
            vv[i] = inb ? *(const float2*)(src + (size_t)(i * 8) * PP)
                        : make_float2(0.f, 0.f);
        #pragma unroll
        for (int i = 0; i < 16; i++) {
            int c = i * 8 + (t >> 5);
            sA[swz128(pos,     c)] = (_Float16)vv[i].x;
            sA[swz128(pos + 1, c)] = (_Float16)vv[i].y;
        }
    }
    __syncthreads();                      // B1: sX ready

    // ---- P2: K,V GEMM over 64 halo positions from held weight frags.
    // K N-tiles {w,w+4} -> sK; V tiles {2w,2w+1} (head w) -> registers.
    h2 vpk[2][4][2];
    #pragma unroll
    for (int m = 0; m < 4; m++) {
        f16x8 A[4];
        #pragma unroll
        for (int kc = 0; kc < 4; kc++)
            A[kc] = *(const f16x8*)(sA + swz128(m * 16 + lm, kc * 32 + quad * 8));
        #pragma unroll
        for (int ni = 0; ni < 4; ni++) {
            f32x4 acc = {0.f, 0.f, 0.f, 0.f};
            #pragma unroll
            for (int kc = 0; kc < 4; kc++)
                acc = __builtin_amdgcn_mfma_f32_16x16x32_f16(
                    A[kc], BKV[ni][kc], acc, 0, 0, 0);
            if (ni < 2) {
                int n = w + 4 * ni;
                #pragma unroll
                for (int r = 0; r < 4; r++)
                    sB[swz128(m * 16 + quad * 4 + r, n * 16 + lm)] = (_Float16)acc[r];
            } else {
                h2 p0, p1;
                p0[0] = (_Float16)acc[0]; p0[1] = (_Float16)acc[1];
                p1[0] = (_Float16)acc[2]; p1[1] = (_Float16)acc[3];
                vpk[ni - 2][m][0] = p0;
                vpk[ni - 2][m][1] = p1;
            }
        }
    }

    // ---- P3a: A-frags for Q (interior halo rows) into regs before sX dies
    f16x8 A3[4];
    {
        int hrow = ((lm >> 2) + 2) * 8 + (lm & 3) + 2;
        #pragma unroll
        for (int kc = 0; kc < 4; kc++)
            A3[kc] = *(const f16x8*)(sA + swz128(hrow, kc * 32 + quad * 8));
    }

    // ---- pre-issue Q weight fragments (global-only dep; in flight across B2)
    f16x8 BQ[2][4];
    #pragma unroll
    for (int nn = 0; nn < 2; nn++) {
        const _Float16* wr = wqkv + (size_t)((2 * w + nn) * 16 + lm) * 128;
        #pragma unroll
        for (int kc = 0; kc < 4; kc++)
            BQ[nn][kc] = *(const f16x8*)(wr + kc * 32 + quad * 8);
    }
    __syncthreads();                      // B2: all sX reads done; sK complete

    // ---- P3b: Q GEMM; wave w computes head w's own Q channels {2w,2w+1}
    _Float16* sQ = sA + 4608;             // bytes 9216..13312
    #pragma unroll
    for (int nn = 0; nn < 2; nn++) {
        f32x4 acc = {0.f, 0.f, 0.f, 0.f};
        #pragma unroll
        for (int kc = 0; kc < 4; kc++)
            acc = __builtin_amdgcn_mfma_f32_16x16x32_f16(
                A3[kc], BQ[nn][kc], acc, 0, 0, 0);
        #pragma unroll
        for (int r = 0; r < 4; r++)
            sQ[swz128(quad * 4 + r, (2 * w + nn) * 16 + lm)] = (_Float16)acc[r];
    }

    // ---- QK^T: S[px=quad*4+r][pos=n*16+lm] fragments (same-wave sQ dep only)
    f32x4 S[4];
    {
        f16x8 Aq = *(const f16x8*)(sQ + swz128(lm, w * 32 + quad * 8));
        #pragma unroll
        for (int n = 0; n < 4; n++) {
            f16x8 Bk = *(const f16x8*)(sB + swz128(n * 16 + lm, w * 32 + quad * 8));
            f32x4 z = {0.f, 0.f, 0.f, 0.f};
            S[n] = __builtin_amdgcn_mfma_f32_16x16x32_f16(Aq, Bk, z, 0, 0, 0);
        }
    }

    // ---- softmax on fragments. px=(quad,r): window = hy in [quad,quad+5),
    // hx in [r,r+5). Reduce over n in-lane + shfl_xor over the 16-lane group.
    _Float16* sPh = sA + w * 1152;        // head slab: 16 rows x 72 halfs
    float inv4[4];
    {
        const float scale = 0.17677669529663689f;
        #pragma unroll
        for (int r = 0; r < 4; r++) {
            float e[4];
            float mx = -1e30f;
            #pragma unroll
            for (int n = 0; n < 4; n++) {
                int hy = n * 2 + (lm >> 3), hx = lm & 7;
                bool memb = (hy >= quad) && (hy < quad + 5) && (hx >= r) && (hx < r + 5);
                e[n] = memb ? S[n][r] * scale : -1e30f;
                mx = fmaxf(mx, e[n]);
            }
            mx = fmaxf(mx, __shfl_xor(mx, 1));
            mx = fmaxf(mx, __shfl_xor(mx, 2));
            mx = fmaxf(mx, __shfl_xor(mx, 4));
            mx = fmaxf(mx, __shfl_xor(mx, 8));
            float sum = 0.f;
            #pragma unroll
            for (int n = 0; n < 4; n++) {
                float ev = __expf(e[n] - mx);   // masked -> exp(-huge) == 0
                e[n] = ev;
                sum += ev;
            }
            sum += __shfl_xor(sum, 1);
            sum += __shfl_xor(sum, 2);
            sum += __shfl_xor(sum, 4);
            sum += __shfl_xor(sum, 8);
            inv4[r] = 1.f / sum;
            #pragma unroll
            for (int n = 0; n < 4; n++)
                sPh[(quad * 4 + r) * 72 + n * 16 + lm] = (_Float16)e[n];
        }
    }

    // ---- pre-issue proj weight fragments (in flight across B3)
    f16x8 Aw[2][4];
    #pragma unroll
    for (int mi = 0; mi < 2; mi++) {
        const _Float16* wr = wp16 + (size_t)((w * 2 + mi) * 16 + lm) * 128;
        #pragma unroll
        for (int kc = 0; kc < 4; kc++)
            Aw[mi][kc] = *(const f16x8*)(wr + kc * 32 + quad * 8);
    }
    __syncthreads();                      // B3: sK reads done; sQ dead

    // ---- stage held V registers into per-wave slab (overlays sK)
    _Float16* sVh = sB + w * 2048;        // V^T[32 d][64 pos] swz
    #pragma unroll
    for (int nn = 0; nn < 2; nn++)
        #pragma unroll
        for (int m = 0; m < 4; m++)
            #pragma unroll
            for (int rp = 0; rp < 2; rp++)
                *(h2*)(sVh + swz64(nn * 16 + lm, m * 16 + quad * 4 + rp * 2))
                    = vpk[nn][m][rp];

    // ---- PV: out[px][d] = (sum_pos P*V) * inv  (all same-wave LDS deps)
    _Float16* sAo = sQ;                   // overlays dead sQ
    {
        f16x8 Ap[2];
        #pragma unroll
        for (int kc = 0; kc < 2; kc++)
            Ap[kc] = *(const f16x8*)(sPh + lm * 72 + kc * 32 + quad * 8);
        #pragma unroll
        for (int nd = 0; nd < 2; nd++) {
            f32x4 acc = {0.f, 0.f, 0.f, 0.f};
            #pragma unroll
            for (int kc = 0; kc < 2; kc++) {
                f16x8 Bv = *(const f16x8*)(sVh + swz64(nd * 16 + lm, kc * 32 + quad * 8));
                acc = __builtin_amdgcn_mfma_f32_16x16x32_f16(Ap[kc], Bv, acc, 0, 0, 0);
            }
            #pragma unroll
            for (int r = 0; r < 4; r++)
                sAo[swz128(quad * 4 + r, w * 32 + nd * 16 + lm)] =
                    (_Float16)(acc[r] * inv4[r]);
        }
    }
    __syncthreads();                      // B4: sAo complete (all heads)

    // ---- proj: out[c][px] = sum_o wp[c][o] * ao[px][o]
    {
        f16x8 Bf[4];
        #pragma unroll
        for (int kc = 0; kc < 4; kc++)
            Bf[kc] = *(const f16x8*)(sAo + swz128(lm, kc * 32 + quad * 8));
        int gp = (y0 + (lm >> 2)) * 96 + x0 + (lm & 3);
        #pragma unroll
        for (int mi = 0; mi < 2; mi++) {
            f32x4 acc = {0.f, 0.f, 0.f, 0.f};
            #pragma unroll
            for (int kc = 0; kc < 4; kc++)
                acc = __builtin_amdgcn_mfma_f32_16x16x32_f16(
                    Aw[mi][kc], Bf[kc], acc, 0, 0, 0);
            int c0 = (w * 2 + mi) * 16 + quad * 4;
            #pragma unroll
            for (int r = 0; r < 4; r++)
                ob[(size_t)(c0 + r) * PP + gp] = acc[r];
        }
    }
}

extern "C" void kernel_launch(void* const* d_in, const int* in_sizes, int n_in,
                              void* d_out, int out_size, void* d_ws, size_t ws_size,
                              hipStream_t stream)
{
    const float* x  = (const float*)d_in[0];
    const float* wq = (const float*)d_in[1];
    const float* wk = (const float*)d_in[2];
    const float* wv = (const float*)d_in[3];
    const float* wp = (const float*)d_in[4];
    float* out = (float*)d_out;

    _Float16* wqkv16 = (_Float16*)d_ws;          // 384*128
    _Float16* wp16   = wqkv16 + 49152;           // 128*128

    prep_w<<<dim3(64), 256, 0, stream>>>(wq, wk, wv, wp, wqkv16, wp16);
    fused_attn<<<dim3(1152), 256, 0, stream>>>(x, wqkv16, wp16, out);
}